// Round 1
// baseline (41.299 us; speedup 1.0000x reference)
//
#include <hip/hip_runtime.h>

// Pairwise Manhattan (L1) distance.
//   A: [N=1024, D=128] f32, B: [M=4096, D=128] f32 -> out: [N, M] f32
// VALU-bound: 1.07e9 fp32 lane-ops -> ~13.7us floor at 78.6e12 ops/s.
//
// Tiling: 64x64 output tile per 256-thread block, 4x4 register tile/thread.
// D staged in chunks of 64 into LDS, TRANSPOSED (lds[d][row]) so the per-d
// fragment read is a single aligned ds_read_b128 (4 rows / 4 cols at once).
// LDS = 32KB/block -> 5 blocks/CU (20 waves/CU).

#define D_DIM 128
#define TN 64
#define TM 64
#define DK 64

__global__ __launch_bounds__(256, 4) void manhattan_l1_kernel(
    const float* __restrict__ A, const float* __restrict__ B,
    float* __restrict__ out, int N, int M)
{
    __shared__ float lds_a[DK][TN];  // [d][row]
    __shared__ float lds_b[DK][TM];  // [d][col]

    const int tid = threadIdx.x;
    const int tx = tid & 15;   // col-group 0..15 (covers 4 cols each)
    const int ty = tid >> 4;   // row-group 0..15 (covers 4 rows each)

    const int row0 = blockIdx.y * TN;
    const int col0 = blockIdx.x * TM;

    // Staging mapping: lane index within block
    const int sr = tid & 63;        // row (for A) / col (for B) 0..63
    const int sd = (tid >> 6) * 4;  // d4 base: 0,4,8,12

    float acc[4][4] = {};

    for (int dk = 0; dk < D_DIM; dk += DK) {
        __syncthreads();  // protect LDS from previous chunk's readers
        // Stage A-tile and B-tile, transposed into LDS.
        // Each thread: 4 float4 global loads per matrix, scalar LDS writes
        // (lane = row -> consecutive addresses -> conflict-free writes).
        #pragma unroll
        for (int j = 0; j < 4; ++j) {
            const int d4 = sd + j * 16;
            float4 va = *reinterpret_cast<const float4*>(
                &A[(size_t)(row0 + sr) * D_DIM + dk + d4]);
            lds_a[d4 + 0][sr] = va.x;
            lds_a[d4 + 1][sr] = va.y;
            lds_a[d4 + 2][sr] = va.z;
            lds_a[d4 + 3][sr] = va.w;
            float4 vb = *reinterpret_cast<const float4*>(
                &B[(size_t)(col0 + sr) * D_DIM + dk + d4]);
            lds_b[d4 + 0][sr] = vb.x;
            lds_b[d4 + 1][sr] = vb.y;
            lds_b[d4 + 2][sr] = vb.z;
            lds_b[d4 + 3][sr] = vb.w;
        }
        __syncthreads();

        // Compute: per d-step, 2x ds_read_b128 + 16 sub + 16 add(abs).
        #pragma unroll 4
        for (int d = 0; d < DK; ++d) {
            const float4 av = *reinterpret_cast<const float4*>(&lds_a[d][ty * 4]);
            const float4 bv = *reinterpret_cast<const float4*>(&lds_b[d][tx * 4]);
            const float a0 = av.x, a1 = av.y, a2 = av.z, a3 = av.w;
            const float b0 = bv.x, b1 = bv.y, b2 = bv.z, b3 = bv.w;
            acc[0][0] += __builtin_fabsf(a0 - b0);
            acc[0][1] += __builtin_fabsf(a0 - b1);
            acc[0][2] += __builtin_fabsf(a0 - b2);
            acc[0][3] += __builtin_fabsf(a0 - b3);
            acc[1][0] += __builtin_fabsf(a1 - b0);
            acc[1][1] += __builtin_fabsf(a1 - b1);
            acc[1][2] += __builtin_fabsf(a1 - b2);
            acc[1][3] += __builtin_fabsf(a1 - b3);
            acc[2][0] += __builtin_fabsf(a2 - b0);
            acc[2][1] += __builtin_fabsf(a2 - b1);
            acc[2][2] += __builtin_fabsf(a2 - b2);
            acc[2][3] += __builtin_fabsf(a2 - b3);
            acc[3][0] += __builtin_fabsf(a3 - b0);
            acc[3][1] += __builtin_fabsf(a3 - b1);
            acc[3][2] += __builtin_fabsf(a3 - b2);
            acc[3][3] += __builtin_fabsf(a3 - b3);
        }
    }

    // Epilogue: coalesced float4 stores (wave row-segment = 256B contiguous).
    #pragma unroll
    for (int i = 0; i < 4; ++i) {
        float4 v;
        v.x = acc[i][0];
        v.y = acc[i][1];
        v.z = acc[i][2];
        v.w = acc[i][3];
        *reinterpret_cast<float4*>(
            &out[(size_t)(row0 + ty * 4 + i) * M + col0 + tx * 4]) = v;
    }
}

extern "C" void kernel_launch(void* const* d_in, const int* in_sizes, int n_in,
                              void* d_out, int out_size, void* d_ws, size_t ws_size,
                              hipStream_t stream) {
    const float* A = (const float*)d_in[0];
    const float* B = (const float*)d_in[1];
    float* out = (float*)d_out;

    const int N = in_sizes[0] / D_DIM;  // 1024
    const int M = in_sizes[1] / D_DIM;  // 4096

    dim3 grid(M / TM, N / TN);  // (64, 16)
    dim3 block(256);
    manhattan_l1_kernel<<<grid, block, 0, stream>>>(A, B, out, N, M);
}